// Round 14
// baseline (1502.604 us; speedup 1.0000x reference)
//
#include <hip/hip_runtime.h>

typedef __attribute__((ext_vector_type(8))) _Float16 f16x8;
typedef __attribute__((ext_vector_type(4))) float    f32x4;

#define HD    256
#define CIN   16
#define TIN   48
#define TOUT  24
#define COUT  8
#define MB    32            // batch rows per block
#define KPAD  296           // padded row stride (halves) for hF
#define KT_ENC 9            // K = 288 (h 256 | x 16 | pad 16)
#define KT_DEC 8            // K = 256
#define NSLOT 7             // per-wave ring slots (1KB frags), continuous ring
#define WE_HALVES (KT_ENC*4*16*512)   // 294912
#define WD_HALVES (KT_DEC*4*16*512)   // 262144
#define PREP_TOTAL (WE_HALVES + WD_HALVES)

template <int N> struct KTag { static constexpr int val = N; };

// Fragment-major fp16 weights: frag id = kt*64 + g*16 + ntile, each frag is
// 64 lanes x 8 halves with b_frag[lane][s] = W[k = kt*32 + (lane>>4)*8 + s]
//                                             [col = g*256 + ntile*16 + (lane&15)]
__global__ void prep_frags(const float* __restrict__ enc_Wih,
                           const float* __restrict__ enc_Whh,
                           const float* __restrict__ dec_Whh,
                           _Float16* __restrict__ wf)
{
    int p = blockIdx.x * blockDim.x + threadIdx.x;
    if (p >= PREP_TOTAL) return;
    int lane = (p >> 3) & 63;
    int s    = p & 7;
    int kq   = ((lane >> 4) << 3) + s;
    int l15  = lane & 15;
    float v;
    if (p < WE_HALVES) {
        int frag = p >> 9;
        int kt = frag >> 6, g = (frag >> 4) & 3, ntile = frag & 15;
        int k   = kt * 32 + kq;
        int row = g * 256 + ntile * 16 + l15;
        v = 0.0f;
        if (k < 256)      v = enc_Whh[row * 256 + k];
        else if (k < 272) v = enc_Wih[row * 16 + (k - 256)];
    } else {
        int q = p - WE_HALVES;
        int frag = q >> 9;
        int kt = frag >> 6, g = (frag >> 4) & 3, ntile = frag & 15;
        int k   = kt * 32 + kq;
        int row = g * 256 + ntile * 16 + l15;
        v = dec_Whh[row * 256 + k];
    }
    wf[p] = (_Float16)v;
}

__device__ __forceinline__ float sigm(float v) {
    return __builtin_amdgcn_rcpf(1.0f + __expf(-v));
}
__device__ __forceinline__ float tanh_f(float v) {
    return 1.0f - 2.0f * __builtin_amdgcn_rcpf(1.0f + __expf(2.0f * v));
}

// Async global->LDS stage of one 1KB weight fragment: 64 lanes x 16B.
__device__ __forceinline__ void gld_lds16(const _Float16* g, _Float16* l) {
    __builtin_amdgcn_global_load_lds(
        (const __attribute__((address_space(1))) void*)g,
        (__attribute__((address_space(3))) void*)l, 16, 0, 0);
}

// grid = 256 blocks (1/CU), 1024 threads = 16 waves. Wave w owns ntile w.
// vs r12 (last-good, 1125us):
//  * hF double-buffered -> ONE full __syncthreads() per step (compiler
//    vmcnt(0)+lgkmcnt(0) drain -- the proven-correct barrier construct).
//  * CONTINUOUS 7-slot weight ring (running slot counter, never reset):
//    the stage stream flows across gemm boundaries, so the next step's first
//    6 frags are issued during the current gemm's TAIL -- latency hides under
//    tail MFMAs + pointwise, the barrier drain finds them landed, and each
//    gemm starts hot (r12 paid a cold ring-fill at every gemm head).
//  * In-loop invariant unchanged from r12: issue stage(pos+6), vmcnt(6),
//    consume pos. Junk VMEM is either pre-barrier (drained) or older than all
//    in-loop stages (retired by the first counted wait) -> conservative.
// LDS 156672 B <= 163840.
__global__ __launch_bounds__(1024, 1) void seq2seq_mfma(
    const float* __restrict__ x,
    const _Float16* __restrict__ wf,
    const float* __restrict__ enc_b,
    const float* __restrict__ dec_b,
    const float* __restrict__ denseW,
    const float* __restrict__ denseb,
    float* __restrict__ out)
{
    __shared__ __align__(16) _Float16 hF[2][MB * KPAD];       // 37888 B
    __shared__ __align__(16) _Float16 Wlds[16][NSLOT][512];   // 114688 B
    __shared__ __align__(16) float    outS4[MB * COUT * 4];   // 4096 B

    const int tid  = threadIdx.x;
    const int w    = tid >> 6;       // 0..15 = ntile
    const int lane = tid & 63;
    const int quad = lane >> 4;
    const int l15  = lane & 15;
    const int n0   = blockIdx.x * MB;

    float bE[4], bD[4];
    #pragma unroll
    for (int g = 0; g < 4; ++g) {
        int col = w * 16 + l15;
        bE[g] = enc_b[g * 256 + col];
        bD[g] = dec_b[g * 256 + col];
    }

    {   // zero both hF buffers (pad cols stay 0 forever)
        _Float16* hz = &hF[0][0];
        for (int i = tid; i < 2 * MB * KPAD; i += 1024) hz[i] = (_Float16)0.0f;
    }
    __syncthreads();
    if (tid < 512) {                 // x for step 0 -> hF[0]
        int m = tid >> 4, c = tid & 15;
        hF[0][m * KPAD + 256 + c] = (_Float16)x[(size_t)(n0 + m) * (CIN * TIN) + c * TIN];
    }
    __syncthreads();

    f32x4 acc[2][4];        // [Mtile][gate]
    float cst[2][4];        // c-state, C-frag layout rows
    #pragma unroll
    for (int mt = 0; mt < 2; ++mt)
        #pragma unroll
        for (int r = 0; r < 4; ++r) cst[mt][r] = 0.0f;

    auto fragptr = [&](const _Float16* __restrict__ Wbase, int f) {
        int kt = f >> 2, g = f & 3;
        return Wbase + (size_t)(kt * 64 + g * 16 + w) * 512 + lane * 8;
    };

    // continuous ring state: rs = slot of the next frag to be consumed.
    // Invariant: stage position = consume position + 6 (slot rs+6 mod 7).
    int rs = 0;
    #pragma unroll
    for (int f = 0; f < 6; ++f)      // prologue: frags 0..5 -> slots 0..5
        gld_lds16(fragptr(wf, f), &Wlds[w][f][0]);

    auto gemm = [&](auto kt_tag, const _Float16* __restrict__ Wcur,
                    const _Float16* __restrict__ Wnext,
                    const float (&bias)[4], const _Float16* __restrict__ hR) {
        constexpr int KT = decltype(kt_tag)::val;
        constexpr int NF = KT * 4;
        #pragma unroll
        for (int mt = 0; mt < 2; ++mt)
            #pragma unroll
            for (int g = 0; g < 4; ++g) {
                float b = bias[g];
                f32x4 bv = {b, b, b, b};
                acc[mt][g] = bv;
            }
        const f16x8* Ap0 = (const f16x8*)(hR + l15 * KPAD);
        const f16x8* Ap1 = (const f16x8*)(hR + (16 + l15) * KPAD);
        f16x8 a0, a1;
        #pragma unroll
        for (int f = 0; f < NF; ++f) {
            {   // stage continuous position f+6 (crosses into next gemm)
                const _Float16* gp = (f + 6 < NF) ? fragptr(Wcur, f + 6)
                                                  : fragptr(Wnext, f + 6 - NF);
                int ss = rs + 6; if (ss >= NSLOT) ss -= NSLOT;
                gld_lds16(gp, &Wlds[w][ss][0]);
            }
            asm volatile("s_waitcnt vmcnt(6)" ::: "memory");
            __builtin_amdgcn_sched_barrier(0);
            if ((f & 3) == 0) {       // f compile-time -> folds
                a0 = Ap0[(f >> 2) * 4 + quad];
                a1 = Ap1[(f >> 2) * 4 + quad];
            }
            f16x8 bf = *(const f16x8*)&Wlds[w][rs][lane * 8];
            constexpr int gg0 = 0;  (void)gg0;
            const int g = f & 3;    // compile-time per unrolled instance
            acc[0][g] = __builtin_amdgcn_mfma_f32_16x16x32_f16(a0, bf, acc[0][g], 0, 0, 0);
            acc[1][g] = __builtin_amdgcn_mfma_f32_16x16x32_f16(a1, bf, acc[1][g], 0, 0, 0);
            rs = (rs + 1 == NSLOT) ? 0 : rs + 1;
        }
    };

    auto pointwise = [&](_Float16* __restrict__ hW) {
        int col = w * 16 + l15;
        #pragma unroll
        for (int mt = 0; mt < 2; ++mt)
            #pragma unroll
            for (int r = 0; r < 4; ++r) {
                float iv = sigm(acc[mt][0][r]);
                float fv = sigm(acc[mt][1][r]);
                float gv = tanh_f(acc[mt][2][r]);
                float ov = sigm(acc[mt][3][r]);
                float cn = fmaf(fv, cst[mt][r], iv * gv);
                cst[mt][r] = cn;
                float hv = ov * tanh_f(cn);
                hW[(mt * 16 + quad * 4 + r) * KPAD + col] = (_Float16)hv;
            }
    };

    const _Float16* wfD = wf + WE_HALVES;

    // ================= encoder (one full barrier per step) =================
    for (int t = 0; t < TIN; ++t) {
        gemm(KTag<KT_ENC>{}, wf, (t + 1 < TIN) ? wf : wfD, bE, hF[t & 1]);
        float xv = 0.0f;
        const bool xl = (tid < 512) && (t + 1 < TIN);
        if (xl)
            xv = x[(size_t)(n0 + (tid >> 4)) * (CIN * TIN) + (tid & 15) * TIN + (t + 1)];
        pointwise(hF[(t + 1) & 1]);
        if (xl) hF[(t + 1) & 1][(tid >> 4) * KPAD + 256 + (tid & 15)] = (_Float16)xv;
        __syncthreads();              // full drain: prestaged frags land here
    }

    // ================= decoder (c resets to 0) =================
    #pragma unroll
    for (int mt = 0; mt < 2; ++mt)
        #pragma unroll
        for (int r = 0; r < 4; ++r) cst[mt][r] = 0.0f;

    for (int t = 0; t < TOUT; ++t) {
        gemm(KTag<KT_DEC>{}, wfD, wfD, bD, hF[t & 1]);   // last step: harmless restage
        pointwise(hF[(t + 1) & 1]);
        __syncthreads();
        // epilogue reads hF[(t+1)&1] (h just produced). Fast waves' gemm(t+1)
        // also READS that buffer; their pointwise(t+1) writes hF[t&1] ->
        // disjoint. Epilogue junk VMEM is older than all of gemm(t+1)'s
        // in-loop stages -> retired by the first counted wait.
        if (tid < MB * COUT) {
            int m = tid >> 3, o = tid & 7;
            const float* wr = denseW + (t * COUT + o) * HD;
            float s = denseb[t * COUT + o];
            const _Float16* hrow = &hF[(t + 1) & 1][m * KPAD];
            #pragma unroll 4
            for (int j8 = 0; j8 < 32; ++j8) {
                f16x8 hv  = *(const f16x8*)(hrow + j8 * 8);
                float4 w0 = *(const float4*)(wr + j8 * 8);
                float4 w1 = *(const float4*)(wr + j8 * 8 + 4);
                s = fmaf((float)hv[0], w0.x, s);
                s = fmaf((float)hv[1], w0.y, s);
                s = fmaf((float)hv[2], w0.z, s);
                s = fmaf((float)hv[3], w0.w, s);
                s = fmaf((float)hv[4], w1.x, s);
                s = fmaf((float)hv[5], w1.y, s);
                s = fmaf((float)hv[6], w1.z, s);
                s = fmaf((float)hv[7], w1.w, s);
            }
            outS4[(tid << 2) | (t & 3)] = s;
            if ((t & 3) == 3) {       // flush 4 finished t-values, 16B-aligned
                float4 v = *(const float4*)&outS4[tid << 2];
                *(float4*)(out + (size_t)(n0 + m) * (COUT * TOUT) + o * TOUT + (t - 3)) = v;
            }
        }
    }
}

extern "C" void kernel_launch(void* const* d_in, const int* in_sizes, int n_in,
                              void* d_out, int out_size, void* d_ws, size_t ws_size,
                              hipStream_t stream) {
    const float* x       = (const float*)d_in[0];
    const float* enc_Wih = (const float*)d_in[1];
    const float* enc_Whh = (const float*)d_in[2];
    const float* enc_b   = (const float*)d_in[3];
    const float* dec_Whh = (const float*)d_in[4];
    const float* dec_b   = (const float*)d_in[5];
    const float* denseW  = (const float*)d_in[6];
    const float* denseb  = (const float*)d_in[7];
    float* out = (float*)d_out;
    _Float16* wf = (_Float16*)d_ws;   // 1.09 MB fragment-major fp16 weights

    prep_frags<<<(PREP_TOTAL + 255) / 256, 256, 0, stream>>>(enc_Wih, enc_Whh, dec_Whh, wf);
    seq2seq_mfma<<<8192 / MB, 1024, 0, stream>>>(x, wf, enc_b, dec_b, denseW, denseb, out);
}